// Round 1
// baseline (1638.512 us; speedup 1.0000x reference)
//
#include <hip/hip_runtime.h>

#define NIMG 8
#define NLVL 5
#define KC 80
#define ANCN 9
#define TK 1000
#define NCAND 5000
#define MAXDET 100
#define NBIN 4096
#define BCAP 32768
#define IMGF 800.0f
#define SCORE_TH 0.05f
#define NMS_TH 0.5f
#define SCLAMP 4.135166556742356f  // log(1000/16)

struct SelE { float v; int idx; };
struct LvlArgs { const float* delta[NLVL]; const float* anc[NLVL]; int HW[NLVL]; };

// ---- workspace byte offsets ----
#define WS_POOLED 0u           // 8*1280 f32            = 40960
#define WS_HIST   40960u       // 40*4096 u32           = 655360
#define WS_SELCNT 696320u      // 40 u32                = 160
#define WS_BNDCNT 696480u      // 40 u32                = 160
#define WS_CUT    696640u      // 40 int2               = 320
#define WS_SEL    696960u      // 40*1000*8             = 320000
#define WS_BND    1016960u     // 40*32768*8            = 10485760
#define WS_CBOX   11502720u    // 8*5000*4 f32          = 640000
#define WS_OBOX   12142720u    // 8*5000*4 f32          = 640000
#define WS_CSC    12782720u    // 8*5000 f32            = 160000
#define WS_KEY    12942720u    // 8*5000 i32            = 160000
#define WS_CCLS   13102720u    // 8*5000 i32            = 160000
// total 13262720 bytes (~12.6 MB)

// monotone float->uint transform: larger float => larger key
__device__ __forceinline__ unsigned mkey(float f){
  unsigned u = __float_as_uint(f);
  return (u & 0x80000000u) ? ~u : (u | 0x80000000u);
}

// ---------------- pooling: mean over H*W per (n, c) ----------------
__global__ void pool_k(const float* __restrict__ feat, float* __restrict__ pooled,
                       int HW, int lvlOff){
  int c = blockIdx.x & 255;
  int n = blockIdx.x >> 8;
  const float* p = feat + ((size_t)(n*256 + c)) * HW;
  float s = 0.f;
  for (int i = threadIdx.x; i < HW; i += 256) s += p[i];
  __shared__ float red[256];
  red[threadIdx.x] = s; __syncthreads();
  for (int o = 128; o > 0; o >>= 1){
    if ((int)threadIdx.x < o) red[threadIdx.x] += red[threadIdx.x + o];
    __syncthreads();
  }
  if (threadIdx.x == 0) pooled[n*(NLVL*256) + lvlOff + c] = red[0] / (float)HW;
}

// ---------------- linear head: logits[n][t] = pooled[n] . w[t] + b[t] ----------------
__global__ void linear_k(const float* __restrict__ pooled, const float* __restrict__ w,
                         const float* __restrict__ b, float* __restrict__ out){
  int n = blockIdx.x / 30, t = blockIdx.x % 30;
  const float* pv = pooled + n*1280;
  const float* wv = w + t*1280;
  float s = 0.f;
  for (int i = threadIdx.x; i < 1280; i += 256) s += pv[i] * wv[i];
  __shared__ float red[256];
  red[threadIdx.x] = s; __syncthreads();
  for (int o = 128; o > 0; o >>= 1){
    if ((int)threadIdx.x < o) red[threadIdx.x] += red[threadIdx.x + o];
    __syncthreads();
  }
  if (threadIdx.x == 0) out[4800 + n*30 + t] = red[0] + b[t];
}

// ---------------- histogram of logit bins per (n) for one level ----------------
__global__ void hist_k(const float* __restrict__ cls, unsigned* __restrict__ hist,
                       int E, int bpi){
  __shared__ unsigned h[NBIN];
  for (int i = threadIdx.x; i < NBIN; i += 256) h[i] = 0;
  __syncthreads();
  int n = blockIdx.x / bpi, bid = blockIdx.x % bpi;
  const float* p = cls + (size_t)n * E;
  for (int i = bid*256 + threadIdx.x; i < E; i += bpi*256)
    atomicAdd(&h[mkey(p[i]) >> 20], 1u);
  __syncthreads();
  unsigned* g = hist + n*NBIN;
  for (int i = threadIdx.x; i < NBIN; i += 256) if (h[i]) atomicAdd(&g[i], h[i]);
}

// ---------------- find cutoff bin B and count-above per (lvl,n) ----------------
__global__ void cutoff_k(const unsigned* __restrict__ hist, int2* __restrict__ cut){
  const unsigned* h = hist + (size_t)blockIdx.x * NBIN;
  int tid = threadIdx.x;
  unsigned loc[16], sum = 0;
  #pragma unroll
  for (int j = 0; j < 16; j++){ loc[j] = h[tid*16 + j]; sum += loc[j]; }
  __shared__ unsigned s[256];
  s[tid] = sum; __syncthreads();
  for (int off = 1; off < 256; off <<= 1){
    unsigned v = (tid + off < 256) ? s[tid + off] : 0;
    __syncthreads();
    s[tid] += v;
    __syncthreads();
  }
  unsigned above = (tid < 255) ? s[tid + 1] : 0;
  unsigned cum = above;
  #pragma unroll
  for (int j = 15; j >= 0; j--){
    unsigned cnt = loc[j];
    if (cum < TK && cum + cnt >= TK) cut[blockIdx.x] = make_int2(tid*16 + j, (int)cum);
    cum += cnt;
  }
}

// ---------------- compact: bins>B -> sel, bin==B -> bnd ----------------
__global__ void compact_k(const float* __restrict__ cls, const int2* __restrict__ cut,
                          SelE* __restrict__ sel, unsigned* __restrict__ selcnt,
                          SelE* __restrict__ bnd, unsigned* __restrict__ bndcnt,
                          int E, int HW, int bpi, int lvl){
  int n = blockIdx.x / bpi, bid = blockIdx.x % bpi;
  int id = lvl*NIMG + n;
  int B = cut[id].x;
  const float* p = cls + (size_t)n * E;
  SelE* selp = sel + (size_t)id * TK;
  SelE* bndp = bnd + (size_t)id * BCAP;
  for (int i = bid*256 + threadIdx.x; i < E; i += bpi*256){
    float f = p[i];
    int bin = (int)(mkey(f) >> 20);
    if (bin >= B){
      int ch = i / HW; int pix = i - ch*HW;
      int a = ch / KC, k = ch - a*KC;
      int idx = (pix*ANCN + a)*KC + k;
      SelE e; e.v = f; e.idx = idx;
      if (bin > B){
        unsigned pos = atomicAdd(&selcnt[id], 1u);
        if (pos < TK) selp[pos] = e;
      } else {
        unsigned pos = atomicAdd(&bndcnt[id], 1u);
        if (pos < BCAP) bndp[pos] = e;
      }
    }
  }
}

// ---------------- boundary select: refined 12-bit hist + exact extract-max ----------------
__global__ void bsel_k(const int2* __restrict__ cut, SelE* __restrict__ sel,
                       const SelE* __restrict__ bnd, const unsigned* __restrict__ bndcnt){
  int id = blockIdx.x;
  int cab = cut[id].y;
  int needed = TK - cab;
  int nb = min((int)bndcnt[id], BCAP);
  if (needed <= 0 || nb <= 0) return;
  const SelE* bp = bnd + (size_t)id * BCAP;
  SelE* sp = sel + (size_t)id * TK + cab;
  int tid = threadIdx.x;

  __shared__ unsigned h[NBIN];
  for (int i = tid; i < NBIN; i += 256) h[i] = 0;
  __syncthreads();
  for (int i = tid; i < nb; i += 256)
    atomicAdd(&h[(mkey(bp[i].v) >> 8) & 0xFFFu], 1u);
  __syncthreads();

  unsigned loc[16], sum = 0;
  #pragma unroll
  for (int j = 0; j < 16; j++){ loc[j] = h[tid*16 + j]; sum += loc[j]; }
  __shared__ unsigned s[256];
  s[tid] = sum; __syncthreads();
  for (int off = 1; off < 256; off <<= 1){
    unsigned v = (tid + off < 256) ? s[tid + off] : 0;
    __syncthreads();
    s[tid] += v;
    __syncthreads();
  }
  unsigned above = (tid < 255) ? s[tid + 1] : 0;
  __shared__ int sB2, sc2;
  unsigned cum = above;
  #pragma unroll
  for (int j = 15; j >= 0; j--){
    unsigned cnt = loc[j];
    if (cum < (unsigned)needed && cum + cnt >= (unsigned)needed){ sB2 = tid*16 + j; sc2 = (int)cum; }
    cum += cnt;
  }
  __syncthreads();
  int B2 = sB2, c2 = sc2;

  __shared__ unsigned ctr;
  if (tid == 0) ctr = 0;
  __syncthreads();
  for (int i = tid; i < nb; i += 256){
    int rb = (int)((mkey(bp[i].v) >> 8) & 0xFFFu);
    if (rb > B2){
      unsigned pos = atomicAdd(&ctr, 1u);
      if (pos < (unsigned)needed) sp[pos] = bp[i];
    }
  }
  __syncthreads();

  int rem = needed - c2;
  // taken-bitmask over nb (<= 32768 -> 1024 words); hist no longer needed
  for (int i = tid; i < 1024; i += 256) h[i] = 0;
  __syncthreads();
  __shared__ float rv[4]; __shared__ int ri[4]; __shared__ int rs[4];
  for (int it = 0; it < rem; it++){
    float bv = -3.4e38f; int bidx = 0x7fffffff; int bslot = 0;
    for (int i = tid; i < nb; i += 256){
      int rb = (int)((mkey(bp[i].v) >> 8) & 0xFFFu);
      if (rb != B2) continue;
      if (h[i >> 5] & (1u << (i & 31))) continue;
      float v = bp[i].v; int ix = bp[i].idx;
      if (v > bv || (v == bv && ix < bidx)){ bv = v; bidx = ix; bslot = i; }
    }
    for (int o = 32; o; o >>= 1){
      float ov = __shfl_down(bv, o); int oi = __shfl_down(bidx, o); int os = __shfl_down(bslot, o);
      if (ov > bv || (ov == bv && oi < bidx)){ bv = ov; bidx = oi; bslot = os; }
    }
    int lane = tid & 63, wq = tid >> 6;
    if (lane == 0){ rv[wq] = bv; ri[wq] = bidx; rs[wq] = bslot; }
    __syncthreads();
    if (tid == 0){
      float xv = rv[0]; int xi = ri[0]; int xs = rs[0];
      #pragma unroll
      for (int q = 1; q < 4; q++)
        if (rv[q] > xv || (rv[q] == xv && ri[q] < xi)){ xv = rv[q]; xi = ri[q]; xs = rs[q]; }
      SelE e; e.v = xv; e.idx = xi;
      sp[c2 + it] = e;
      h[xs >> 5] |= (1u << (xs & 31));
    }
    __syncthreads();
  }
}

// ---------------- decode selected candidates ----------------
__global__ void decode_k(const SelE* __restrict__ sel, LvlArgs la,
                         float* __restrict__ cbox, float* __restrict__ obox,
                         float* __restrict__ csc, int* __restrict__ key,
                         int* __restrict__ ccls){
  int g = blockIdx.x*256 + threadIdx.x;
  if (g >= NLVL*NIMG*TK) return;
  int lvl = g / (NIMG*TK); int r = g - lvl*(NIMG*TK);
  int n = r / TK; int j = r - n*TK;
  SelE e = sel[(size_t)(lvl*NIMG + n)*TK + j];
  int idx = e.idx;
  int aidx = idx / KC, k = idx - aidx*KC;
  int a = aidx % ANCN, pix = aidx / ANCN;
  int HW = la.HW[lvl];
  const float* dp = la.delta[lvl] + (size_t)n * (ANCN*4) * HW;
  float dx = dp[(a*4 + 0)*HW + pix];
  float dy = dp[(a*4 + 1)*HW + pix];
  float dw = dp[(a*4 + 2)*HW + pix];
  float dh = dp[(a*4 + 3)*HW + pix];
  const float* ap = la.anc[lvl] + (size_t)aidx * 4;
  float ax1 = ap[0], ay1 = ap[1], ax2 = ap[2], ay2 = ap[3];
  float aw = ax2 - ax1, ah = ay2 - ay1;
  float acx = ax1 + 0.5f*aw, acy = ay1 + 0.5f*ah;
  dw = fminf(dw, SCLAMP); dh = fminf(dh, SCLAMP);
  float pcx = dx*aw + acx, pcy = dy*ah + acy;
  float pw = expf(dw)*aw, ph = expf(dh)*ah;
  float x1 = pcx - 0.5f*pw, y1 = pcy - 0.5f*ph;
  float x2 = pcx + 0.5f*pw, y2 = pcy + 0.5f*ph;
  x1 = fminf(fmaxf(x1, 0.f), IMGF); y1 = fminf(fmaxf(y1, 0.f), IMGF);
  x2 = fminf(fmaxf(x2, 0.f), IMGF); y2 = fminf(fmaxf(y2, 0.f), IMGF);
  float score = 1.f / (1.f + expf(-e.v));
  if (!(score > SCORE_TH)) score = 0.f;
  int slot = n*NCAND + lvl*TK + j;
  cbox[slot*4 + 0] = x1; cbox[slot*4 + 1] = y1; cbox[slot*4 + 2] = x2; cbox[slot*4 + 3] = y2;
  float off = (float)k * (IMGF + 1.0f);
  obox[slot*4 + 0] = x1 + off; obox[slot*4 + 1] = y1 + off;
  obox[slot*4 + 2] = x2 + off; obox[slot*4 + 3] = y2 + off;
  csc[slot] = score;
  key[slot] = (lvl << 23) | idx;   // mirrors reference concatenated-position order on ties
  ccls[slot] = k;
}

// ---------------- greedy NMS, one block per image ----------------
__global__ void __launch_bounds__(256) nms_k(const float* __restrict__ cbox,
                      const float* __restrict__ obox, const float* __restrict__ csc,
                      const int* __restrict__ key, const int* __restrict__ ccls,
                      float* __restrict__ out){
  int n = blockIdx.x;
  int tid = threadIdx.x;
  __shared__ float live[NCAND];
  __shared__ int lkey[NCAND];
  for (int c = tid; c < NCAND; c += 256){
    live[c] = csc[(size_t)n*NCAND + c];
    lkey[c] = key[(size_t)n*NCAND + c];
  }
  __shared__ float rv[4]; __shared__ int rk[4]; __shared__ int rc[4];
  __shared__ float s_jv; __shared__ float pb[5];
  __syncthreads();
  const float* ob = obox + (size_t)n*NCAND*4;
  const float* cb = cbox + (size_t)n*NCAND*4;
  for (int it = 0; it < MAXDET; it++){
    float bv = -1.f; int bk = 0x7fffffff; int bc = 0;
    for (int c = tid; c < NCAND; c += 256){
      float v = live[c]; int kk = lkey[c];
      if (v > bv || (v == bv && kk < bk)){ bv = v; bk = kk; bc = c; }
    }
    for (int o = 32; o; o >>= 1){
      float ov = __shfl_down(bv, o); int ok = __shfl_down(bk, o); int oc = __shfl_down(bc, o);
      if (ov > bv || (ov == bv && ok < bk)){ bv = ov; bk = ok; bc = oc; }
    }
    int lane = tid & 63, wq = tid >> 6;
    if (lane == 0){ rv[wq] = bv; rk[wq] = bk; rc[wq] = bc; }
    __syncthreads();
    if (tid == 0){
      float xv = rv[0]; int xk = rk[0]; int xc = rc[0];
      #pragma unroll
      for (int q = 1; q < 4; q++)
        if (rv[q] > xv || (rv[q] == xv && rk[q] < xk)){ xv = rv[q]; xk = rk[q]; xc = rc[q]; }
      s_jv = xv;
      float4 b = *(const float4*)&ob[(size_t)xc*4];
      float area = (b.z - b.x)*(b.w - b.y);
      pb[0] = b.x; pb[1] = b.y; pb[2] = b.z; pb[3] = b.w; pb[4] = area;
      float* obx = out + (size_t)(n*MAXDET + it)*4;
      if (xv > 0.f){
        float4 bo = *(const float4*)&cb[(size_t)xc*4];
        int cls = ccls[(size_t)n*NCAND + xc];
        obx[0] = bo.x; obx[1] = bo.y; obx[2] = bo.z; obx[3] = bo.w;
        out[3200 + n*MAXDET + it] = xv;
        out[4000 + n*MAXDET + it] = (float)cls;
      } else {
        obx[0] = 0.f; obx[1] = 0.f; obx[2] = 0.f; obx[3] = 0.f;
        out[3200 + n*MAXDET + it] = 0.f;
        out[4000 + n*MAXDET + it] = -1.f;
      }
      live[xc] = 0.f;
    }
    __syncthreads();
    if (s_jv > 0.f){
      float px1 = pb[0], py1 = pb[1], px2 = pb[2], py2 = pb[3], pa = pb[4];
      for (int c = tid; c < NCAND; c += 256){
        if (live[c] <= 0.f) continue;
        float4 b = *(const float4*)&ob[(size_t)c*4];
        float ix1 = fmaxf(px1, b.x), iy1 = fmaxf(py1, b.y);
        float ix2 = fminf(px2, b.z), iy2 = fminf(py2, b.w);
        float inter = fmaxf(ix2 - ix1, 0.f) * fmaxf(iy2 - iy1, 0.f);
        float area = (b.z - b.x)*(b.w - b.y);
        float iou = inter / (pa + area - inter + 1e-9f);
        if (iou > NMS_TH) live[c] = 0.f;
      }
    }
    __syncthreads();
  }
}

extern "C" void kernel_launch(void* const* d_in, const int* in_sizes, int n_in,
                              void* d_out, int out_size, void* d_ws, size_t ws_size,
                              hipStream_t stream){
  (void)in_sizes; (void)n_in; (void)out_size; (void)ws_size;
  const float* feat[5]; const float* cls[5]; const float* del[5]; const float* anc[5];
  for (int i = 0; i < 5; i++){
    feat[i] = (const float*)d_in[4*i + 0];
    cls[i]  = (const float*)d_in[4*i + 1];
    del[i]  = (const float*)d_in[4*i + 2];
    anc[i]  = (const float*)d_in[4*i + 3];
  }
  const float* lw = (const float*)d_in[20];
  const float* lb = (const float*)d_in[21];
  float* out = (float*)d_out;
  char* ws = (char*)d_ws;
  float*    pooled = (float*)(ws + WS_POOLED);
  unsigned* hist   = (unsigned*)(ws + WS_HIST);
  unsigned* selcnt = (unsigned*)(ws + WS_SELCNT);
  unsigned* bndcnt = (unsigned*)(ws + WS_BNDCNT);
  int2*     cut    = (int2*)(ws + WS_CUT);
  SelE*     sel    = (SelE*)(ws + WS_SEL);
  SelE*     bnd    = (SelE*)(ws + WS_BND);
  float*    cbox   = (float*)(ws + WS_CBOX);
  float*    obox   = (float*)(ws + WS_OBOX);
  float*    csc    = (float*)(ws + WS_CSC);
  int*      key    = (int*)(ws + WS_KEY);
  int*      ccl    = (int*)(ws + WS_CCLS);

  static const int HWs[5] = {10000, 2500, 625, 169, 49};

  // zero hist + selcnt + bndcnt (contiguous region)
  hipMemsetAsync(ws + WS_HIST, 0, 655680, stream);

  for (int i = 0; i < 5; i++)
    pool_k<<<NIMG*256, 256, 0, stream>>>(feat[i], pooled, HWs[i], i*256);
  linear_k<<<NIMG*30, 256, 0, stream>>>(pooled, lw, lb, out);

  for (int i = 0; i < 5; i++){
    int E = 720 * HWs[i];
    int bpi = (E + 256*128 - 1) / (256*128);
    hist_k<<<NIMG*bpi, 256, 0, stream>>>(cls[i], hist + (size_t)i*NIMG*NBIN, E, bpi);
  }
  cutoff_k<<<NLVL*NIMG, 256, 0, stream>>>(hist, cut);
  for (int i = 0; i < 5; i++){
    int E = 720 * HWs[i];
    int bpi = (E + 256*128 - 1) / (256*128);
    compact_k<<<NIMG*bpi, 256, 0, stream>>>(cls[i], cut, sel, selcnt, bnd, bndcnt,
                                            E, HWs[i], bpi, i);
  }
  bsel_k<<<NLVL*NIMG, 256, 0, stream>>>(cut, sel, bnd, bndcnt);

  LvlArgs la;
  for (int i = 0; i < 5; i++){ la.delta[i] = del[i]; la.anc[i] = anc[i]; la.HW[i] = HWs[i]; }
  decode_k<<<(NLVL*NIMG*TK + 255)/256, 256, 0, stream>>>(sel, la, cbox, obox, csc, key, ccl);
  nms_k<<<NIMG, 256, 0, stream>>>(cbox, obox, csc, key, ccl, out);
}

// Round 2
// 1358.038 us; speedup vs baseline: 1.2065x; 1.2065x over previous
//
#include <hip/hip_runtime.h>

#define NIMG 8
#define NLVL 5
#define KC 80
#define ANCN 9
#define TK 1000
#define NCAND 5000
#define MAXDET 100
#define NBIN 4096
#define BCAP 32768
#define IMGF 800.0f
#define SCORE_TH 0.05f
#define NMS_TH 0.5f
#define SCLAMP 4.135166556742356f  // log(1000/16)

struct SelE { float v; int idx; };
struct LvlArgs { const float* delta[NLVL]; const float* anc[NLVL]; int HW[NLVL]; };

// ---- workspace byte offsets ----
#define WS_POOLED 0u           // 8*1280 f32            = 40960
#define WS_HIST   40960u       // 40*4096 u32           = 655360
#define WS_SELCNT 696320u      // 40 u32                = 160
#define WS_BNDCNT 696480u      // 40 u32                = 160
#define WS_CUT    696640u      // 40 int2               = 320
#define WS_SEL    696960u      // 40*1000*8             = 320000
#define WS_BND    1016960u     // 40*32768*8            = 10485760
#define WS_CBOX   11502720u    // 8*5000*4 f32          = 640000
#define WS_OBOX   12142720u    // 8*5000*4 f32          = 640000
#define WS_CSC    12782720u    // 8*5000 f32            = 160000
#define WS_KEY    12942720u    // 8*5000 i32            = 160000
#define WS_CCLS   13102720u    // 8*5000 i32            = 160000
// total 13262720 bytes (~12.6 MB)

// monotone float->uint transform: larger float => larger key
__device__ __forceinline__ unsigned mkey(float f){
  unsigned u = __float_as_uint(f);
  return (u & 0x80000000u) ? ~u : (u | 0x80000000u);
}

// ---------------- pooling: mean over H*W per (n, c) ----------------
__global__ void pool_k(const float* __restrict__ feat, float* __restrict__ pooled,
                       int HW, int lvlOff){
  int c = blockIdx.x & 255;
  int n = blockIdx.x >> 8;
  const float* p = feat + ((size_t)(n*256 + c)) * HW;
  float s = 0.f;
  for (int i = threadIdx.x; i < HW; i += 256) s += p[i];
  __shared__ float red[256];
  red[threadIdx.x] = s; __syncthreads();
  for (int o = 128; o > 0; o >>= 1){
    if ((int)threadIdx.x < o) red[threadIdx.x] += red[threadIdx.x + o];
    __syncthreads();
  }
  if (threadIdx.x == 0) pooled[n*(NLVL*256) + lvlOff + c] = red[0] / (float)HW;
}

// ---------------- linear head ----------------
__global__ void linear_k(const float* __restrict__ pooled, const float* __restrict__ w,
                         const float* __restrict__ b, float* __restrict__ out){
  int n = blockIdx.x / 30, t = blockIdx.x % 30;
  const float* pv = pooled + n*1280;
  const float* wv = w + t*1280;
  float s = 0.f;
  for (int i = threadIdx.x; i < 1280; i += 256) s += pv[i] * wv[i];
  __shared__ float red[256];
  red[threadIdx.x] = s; __syncthreads();
  for (int o = 128; o > 0; o >>= 1){
    if ((int)threadIdx.x < o) red[threadIdx.x] += red[threadIdx.x + o];
    __syncthreads();
  }
  if (threadIdx.x == 0) out[4800 + n*30 + t] = red[0] + b[t];
}

// ---------------- histogram: 4-way lane-salted replicas + float4 loads ----------------
__global__ void hist_k(const float* __restrict__ cls, unsigned* __restrict__ hist,
                       int E4, int bpi){
  __shared__ unsigned h[NBIN][4];
  for (int i = threadIdx.x; i < NBIN*4; i += 256) ((unsigned*)h)[i] = 0;
  __syncthreads();
  int n = blockIdx.x / bpi, bid = blockIdx.x % bpi;
  const float4* p = (const float4*)(cls + (size_t)n * ((size_t)E4*4));
  int rep = threadIdx.x & 3;
  for (int i = bid*256 + threadIdx.x; i < E4; i += bpi*256){
    float4 v = p[i];
    atomicAdd(&h[mkey(v.x) >> 20][rep], 1u);
    atomicAdd(&h[mkey(v.y) >> 20][rep], 1u);
    atomicAdd(&h[mkey(v.z) >> 20][rep], 1u);
    atomicAdd(&h[mkey(v.w) >> 20][rep], 1u);
  }
  __syncthreads();
  unsigned* g = hist + n*NBIN;
  for (int i = threadIdx.x; i < NBIN; i += 256){
    unsigned s2 = h[i][0] + h[i][1] + h[i][2] + h[i][3];
    if (s2) atomicAdd(&g[i], s2);
  }
}

// ---------------- find cutoff bin B and count-above per (lvl,n) ----------------
__global__ void cutoff_k(const unsigned* __restrict__ hist, int2* __restrict__ cut){
  const unsigned* h = hist + (size_t)blockIdx.x * NBIN;
  int tid = threadIdx.x;
  unsigned loc[16], sum = 0;
  #pragma unroll
  for (int j = 0; j < 16; j++){ loc[j] = h[tid*16 + j]; sum += loc[j]; }
  __shared__ unsigned s[256];
  s[tid] = sum; __syncthreads();
  for (int off = 1; off < 256; off <<= 1){
    unsigned v = (tid + off < 256) ? s[tid + off] : 0;
    __syncthreads();
    s[tid] += v;
    __syncthreads();
  }
  unsigned above = (tid < 255) ? s[tid + 1] : 0;
  unsigned cum = above;
  #pragma unroll
  for (int j = 15; j >= 0; j--){
    unsigned cnt = loc[j];
    if (cum < TK && cum + cnt >= TK) cut[blockIdx.x] = make_int2(tid*16 + j, (int)cum);
    cum += cnt;
  }
}

// ---------------- compact with wave-aggregated atomics ----------------
__global__ void compact_k(const float* __restrict__ cls, const int2* __restrict__ cut,
                          SelE* __restrict__ sel, unsigned* __restrict__ selcnt,
                          SelE* __restrict__ bnd, unsigned* __restrict__ bndcnt,
                          int E, int HW, int bpi, int lvl){
  int n = blockIdx.x / bpi, bid = blockIdx.x % bpi;
  int id = lvl*NIMG + n;
  int B = cut[id].x;
  const float* p = cls + (size_t)n * E;
  SelE* selp = sel + (size_t)id * TK;
  SelE* bndp = bnd + (size_t)id * BCAP;
  int lane = threadIdx.x & 63;
  for (int i = bid*256 + threadIdx.x; i < E; i += bpi*256){
    float f = p[i];
    int bin = (int)(mkey(f) >> 20);
    bool sF = bin > B, bF = bin == B;
    unsigned long long mS = __ballot(sF);
    unsigned long long mB = __ballot(bF);
    SelE e;
    if (sF || bF){
      int ch = i / HW; int pix = i - ch*HW;
      int a = ch / KC, k = ch - a*KC;
      e.v = f; e.idx = (pix*ANCN + a)*KC + k;
    }
    if (mS){
      int leader = __ffsll((unsigned long long)mS) - 1;
      unsigned base2 = 0;
      if (lane == leader) base2 = atomicAdd(&selcnt[id], (unsigned)__popcll(mS));
      base2 = (unsigned)__shfl((int)base2, leader, 64);
      if (sF){
        unsigned pos = base2 + (unsigned)__popcll(mS & ((1ull << lane) - 1ull));
        if (pos < TK) selp[pos] = e;
      }
    }
    if (mB){
      int leader = __ffsll((unsigned long long)mB) - 1;
      unsigned base2 = 0;
      if (lane == leader) base2 = atomicAdd(&bndcnt[id], (unsigned)__popcll(mB));
      base2 = (unsigned)__shfl((int)base2, leader, 64);
      if (bF){
        unsigned pos = base2 + (unsigned)__popcll(mB & ((1ull << lane) - 1ull));
        if (pos < BCAP) bndp[pos] = e;
      }
    }
  }
}

// ---------------- boundary select: refined 12-bit hist + exact extract-max ----------------
__global__ void bsel_k(const int2* __restrict__ cut, SelE* __restrict__ sel,
                       const SelE* __restrict__ bnd, const unsigned* __restrict__ bndcnt){
  int id = blockIdx.x;
  int cab = cut[id].y;
  int needed = TK - cab;
  int nb = min((int)bndcnt[id], BCAP);
  if (needed <= 0 || nb <= 0) return;
  const SelE* bp = bnd + (size_t)id * BCAP;
  SelE* sp = sel + (size_t)id * TK + cab;
  int tid = threadIdx.x;

  __shared__ unsigned h[NBIN];
  for (int i = tid; i < NBIN; i += 256) h[i] = 0;
  __syncthreads();
  for (int i = tid; i < nb; i += 256)
    atomicAdd(&h[(mkey(bp[i].v) >> 8) & 0xFFFu], 1u);
  __syncthreads();

  unsigned loc[16], sum = 0;
  #pragma unroll
  for (int j = 0; j < 16; j++){ loc[j] = h[tid*16 + j]; sum += loc[j]; }
  __shared__ unsigned s[256];
  s[tid] = sum; __syncthreads();
  for (int off = 1; off < 256; off <<= 1){
    unsigned v = (tid + off < 256) ? s[tid + off] : 0;
    __syncthreads();
    s[tid] += v;
    __syncthreads();
  }
  unsigned above = (tid < 255) ? s[tid + 1] : 0;
  __shared__ int sB2, sc2;
  unsigned cum = above;
  #pragma unroll
  for (int j = 15; j >= 0; j--){
    unsigned cnt = loc[j];
    if (cum < (unsigned)needed && cum + cnt >= (unsigned)needed){ sB2 = tid*16 + j; sc2 = (int)cum; }
    cum += cnt;
  }
  __syncthreads();
  int B2 = sB2, c2 = sc2;

  __shared__ unsigned ctr;
  if (tid == 0) ctr = 0;
  __syncthreads();
  for (int i = tid; i < nb; i += 256){
    int rb = (int)((mkey(bp[i].v) >> 8) & 0xFFFu);
    if (rb > B2){
      unsigned pos = atomicAdd(&ctr, 1u);
      if (pos < (unsigned)needed) sp[pos] = bp[i];
    }
  }
  __syncthreads();

  int rem = needed - c2;
  for (int i = tid; i < 1024; i += 256) h[i] = 0;
  __syncthreads();
  __shared__ float rv[4]; __shared__ int ri[4]; __shared__ int rs[4];
  for (int it = 0; it < rem; it++){
    float bv = -3.4e38f; int bidx = 0x7fffffff; int bslot = 0;
    for (int i = tid; i < nb; i += 256){
      int rb = (int)((mkey(bp[i].v) >> 8) & 0xFFFu);
      if (rb != B2) continue;
      if (h[i >> 5] & (1u << (i & 31))) continue;
      float v = bp[i].v; int ix = bp[i].idx;
      if (v > bv || (v == bv && ix < bidx)){ bv = v; bidx = ix; bslot = i; }
    }
    for (int o = 32; o; o >>= 1){
      float ov = __shfl_down(bv, o); int oi = __shfl_down(bidx, o); int os = __shfl_down(bslot, o);
      if (ov > bv || (ov == bv && oi < bidx)){ bv = ov; bidx = oi; bslot = os; }
    }
    int lane = tid & 63, wq = tid >> 6;
    if (lane == 0){ rv[wq] = bv; ri[wq] = bidx; rs[wq] = bslot; }
    __syncthreads();
    if (tid == 0){
      float xv = rv[0]; int xi = ri[0]; int xs = rs[0];
      #pragma unroll
      for (int q = 1; q < 4; q++)
        if (rv[q] > xv || (rv[q] == xv && ri[q] < xi)){ xv = rv[q]; xi = ri[q]; xs = rs[q]; }
      SelE e; e.v = xv; e.idx = xi;
      sp[c2 + it] = e;
      h[xs >> 5] |= (1u << (xs & 31));
    }
    __syncthreads();
  }
}

// ---------------- decode selected candidates ----------------
__global__ void decode_k(const SelE* __restrict__ sel, LvlArgs la,
                         float* __restrict__ cbox, float* __restrict__ obox,
                         float* __restrict__ csc, int* __restrict__ key,
                         int* __restrict__ ccls){
  int g = blockIdx.x*256 + threadIdx.x;
  if (g >= NLVL*NIMG*TK) return;
  int lvl = g / (NIMG*TK); int r = g - lvl*(NIMG*TK);
  int n = r / TK; int j = r - n*TK;
  SelE e = sel[(size_t)(lvl*NIMG + n)*TK + j];
  int idx = e.idx;
  int aidx = idx / KC, k = idx - aidx*KC;
  int a = aidx % ANCN, pix = aidx / ANCN;
  int HW = la.HW[lvl];
  const float* dp = la.delta[lvl] + (size_t)n * (ANCN*4) * HW;
  float dx = dp[(a*4 + 0)*HW + pix];
  float dy = dp[(a*4 + 1)*HW + pix];
  float dw = dp[(a*4 + 2)*HW + pix];
  float dh = dp[(a*4 + 3)*HW + pix];
  const float* ap = la.anc[lvl] + (size_t)aidx * 4;
  float ax1 = ap[0], ay1 = ap[1], ax2 = ap[2], ay2 = ap[3];
  float aw = ax2 - ax1, ah = ay2 - ay1;
  float acx = ax1 + 0.5f*aw, acy = ay1 + 0.5f*ah;
  dw = fminf(dw, SCLAMP); dh = fminf(dh, SCLAMP);
  float pcx = dx*aw + acx, pcy = dy*ah + acy;
  float pw = expf(dw)*aw, ph = expf(dh)*ah;
  float x1 = pcx - 0.5f*pw, y1 = pcy - 0.5f*ph;
  float x2 = pcx + 0.5f*pw, y2 = pcy + 0.5f*ph;
  x1 = fminf(fmaxf(x1, 0.f), IMGF); y1 = fminf(fmaxf(y1, 0.f), IMGF);
  x2 = fminf(fmaxf(x2, 0.f), IMGF); y2 = fminf(fmaxf(y2, 0.f), IMGF);
  float score = 1.f / (1.f + expf(-e.v));
  if (!(score > SCORE_TH)) score = 0.f;
  int slot = n*NCAND + lvl*TK + j;
  cbox[slot*4 + 0] = x1; cbox[slot*4 + 1] = y1; cbox[slot*4 + 2] = x2; cbox[slot*4 + 3] = y2;
  float off = (float)k * (IMGF + 1.0f);
  obox[slot*4 + 0] = x1 + off; obox[slot*4 + 1] = y1 + off;
  obox[slot*4 + 2] = x2 + off; obox[slot*4 + 3] = y2 + off;
  csc[slot] = score;
  key[slot] = (lvl << 23) | idx;
  ccls[slot] = k;
}

// ---------------- NMS: bitonic sort + chunked forward scan ----------------
__global__ void __launch_bounds__(256) nms2_k(const float* __restrict__ cbox,
                      const float* __restrict__ obox, const float* __restrict__ csc,
                      const int* __restrict__ key, const int* __restrict__ ccls,
                      float* __restrict__ out){
  int n = blockIdx.x;
  int tid = threadIdx.x;
  __shared__ unsigned long long skey[8192];
  __shared__ unsigned short sidx[8192];
  // kept state
  __shared__ float kx1[MAXDET], ky1[MAXDET], kx2[MAXDET], ky2[MAXDET], kar[MAXDET];
  __shared__ float kscore[MAXDET];
  __shared__ unsigned short kslotA[MAXDET];
  // chunk state
  __shared__ float cx1[64], cy1[64], cx2[64], cy2[64], car[64], cscs[64];
  __shared__ unsigned short cslot[64];
  __shared__ unsigned sup[2];
  __shared__ unsigned cm[64][2];
  __shared__ int s_nk, s_stop;

  // load + build sort keys (ascending sort; best candidate = smallest key)
  for (int i = tid; i < 8192; i += 256){
    unsigned long long sk = ~0ull;
    if (i < NCAND){
      int slot = n*NCAND + i;
      float sc = csc[slot];
      unsigned kv = (unsigned)key[slot];
      sk = ~(((unsigned long long)mkey(sc) << 26) | (unsigned long long)(0x3FFFFFFu - kv));
    }
    skey[i] = sk;
    sidx[i] = (unsigned short)i;
  }
  if (tid == 0){ s_nk = 0; s_stop = 0; }

  // bitonic sort ascending
  for (int kk = 2; kk <= 8192; kk <<= 1){
    for (int j = kk >> 1; j > 0; j >>= 1){
      __syncthreads();
      for (int p = tid; p < 4096; p += 256){
        int m = j - 1;
        int a = ((p & ~m) << 1) | (p & m);
        int b = a | j;
        bool up = ((a & kk) == 0);
        unsigned long long ka = skey[a], kb = skey[b];
        bool sw = up ? (ka > kb) : (ka < kb);
        if (sw){
          skey[a] = kb; skey[b] = ka;
          unsigned short t2 = sidx[a]; sidx[a] = sidx[b]; sidx[b] = t2;
        }
      }
    }
  }

  const float* ob = obox;
  // chunked greedy scan
  for (int base = 0; base < NCAND; base += 64){
    __syncthreads();
    if (s_nk >= MAXDET || s_stop) break;
    int vc = min(64, NCAND - base);
    if (tid < 64){
      float sc = -1.f, x1 = 0.f, y1 = 0.f, x2 = 0.f, y2 = 0.f;
      unsigned short ci = 0;
      if (tid < vc){
        ci = sidx[base + tid];
        int slot = n*NCAND + (int)ci;
        sc = csc[slot];
        float4 b = *(const float4*)&ob[(size_t)slot*4];
        x1 = b.x; y1 = b.y; x2 = b.z; y2 = b.w;
      }
      cslot[tid] = ci; cscs[tid] = sc;
      cx1[tid] = x1; cy1[tid] = y1; cx2[tid] = x2; cy2[tid] = y2;
      car[tid] = (x2 - x1) * (y2 - y1);
    }
    if (tid < 2) sup[tid] = 0;
    if (tid < 128) cm[tid >> 1][tid & 1] = 0;
    __syncthreads();
    // suppression by already-kept boxes
    {
      int j = tid & 63, g = tid >> 6;
      if (j < vc && cscs[j] > 0.f){
        float bx1 = cx1[j], by1 = cy1[j], bx2 = cx2[j], by2 = cy2[j], ba = car[j];
        for (int kk2 = g; kk2 < s_nk; kk2 += 4){
          float ix1 = fmaxf(kx1[kk2], bx1), iy1 = fmaxf(ky1[kk2], by1);
          float ix2 = fminf(kx2[kk2], bx2), iy2 = fminf(ky2[kk2], by2);
          float inter = fmaxf(ix2 - ix1, 0.f) * fmaxf(iy2 - iy1, 0.f);
          float iou = inter / (kar[kk2] + ba - inter + 1e-9f);
          if (iou > NMS_TH){ atomicOr(&sup[j >> 5], 1u << (j & 31)); break; }
        }
      }
    }
    // intra-chunk pairwise masks
    for (int p = tid; p < 4096; p += 256){
      int i2 = p >> 6, j2 = p & 63;
      if (j2 > i2 && j2 < vc && cscs[i2] > 0.f && cscs[j2] > 0.f){
        float ix1 = fmaxf(cx1[i2], cx1[j2]), iy1 = fmaxf(cy1[i2], cy1[j2]);
        float ix2 = fminf(cx2[i2], cx2[j2]), iy2 = fminf(cy2[i2], cy2[j2]);
        float inter = fmaxf(ix2 - ix1, 0.f) * fmaxf(iy2 - iy1, 0.f);
        float iou = inter / (car[i2] + car[j2] - inter + 1e-9f);
        if (iou > NMS_TH) atomicOr(&cm[i2][j2 >> 5], 1u << (j2 & 31));
      }
    }
    __syncthreads();
    if (tid == 0){
      unsigned a0 = ~sup[0], a1 = ~sup[1];
      int nk2 = s_nk;
      for (int i3 = 0; i3 < vc; i3++){
        float sc = cscs[i3];
        if (sc <= 0.f){ s_stop = 1; break; }
        unsigned alive = (i3 < 32) ? (a0 >> i3) : (a1 >> (i3 - 32));
        if (alive & 1u){
          kx1[nk2] = cx1[i3]; ky1[nk2] = cy1[i3];
          kx2[nk2] = cx2[i3]; ky2[nk2] = cy2[i3];
          kar[nk2] = car[i3];
          kscore[nk2] = sc; kslotA[nk2] = cslot[i3];
          nk2++;
          a0 &= ~cm[i3][0]; a1 &= ~cm[i3][1];
          if (nk2 >= MAXDET) break;
        }
      }
      s_nk = nk2;
    }
  }
  __syncthreads();
  // write outputs
  for (int it = tid; it < MAXDET; it += 256){
    float bx = 0.f, by = 0.f, bz = 0.f, bw = 0.f, sc = 0.f, cf = -1.f;
    if (it < s_nk){
      int slot = n*NCAND + (int)kslotA[it];
      float4 b = *(const float4*)&cbox[(size_t)slot*4];
      bx = b.x; by = b.y; bz = b.z; bw = b.w;
      sc = kscore[it];
      cf = (float)ccls[slot];
    }
    float* op = out + (size_t)(n*MAXDET + it)*4;
    op[0] = bx; op[1] = by; op[2] = bz; op[3] = bw;
    out[3200 + n*MAXDET + it] = sc;
    out[4000 + n*MAXDET + it] = cf;
  }
}

extern "C" void kernel_launch(void* const* d_in, const int* in_sizes, int n_in,
                              void* d_out, int out_size, void* d_ws, size_t ws_size,
                              hipStream_t stream){
  (void)in_sizes; (void)n_in; (void)out_size; (void)ws_size;
  const float* feat[5]; const float* cls[5]; const float* del[5]; const float* anc[5];
  for (int i = 0; i < 5; i++){
    feat[i] = (const float*)d_in[4*i + 0];
    cls[i]  = (const float*)d_in[4*i + 1];
    del[i]  = (const float*)d_in[4*i + 2];
    anc[i]  = (const float*)d_in[4*i + 3];
  }
  const float* lw = (const float*)d_in[20];
  const float* lb = (const float*)d_in[21];
  float* out = (float*)d_out;
  char* ws = (char*)d_ws;
  float*    pooled = (float*)(ws + WS_POOLED);
  unsigned* hist   = (unsigned*)(ws + WS_HIST);
  unsigned* selcnt = (unsigned*)(ws + WS_SELCNT);
  unsigned* bndcnt = (unsigned*)(ws + WS_BNDCNT);
  int2*     cut    = (int2*)(ws + WS_CUT);
  SelE*     sel    = (SelE*)(ws + WS_SEL);
  SelE*     bnd    = (SelE*)(ws + WS_BND);
  float*    cbox   = (float*)(ws + WS_CBOX);
  float*    obox   = (float*)(ws + WS_OBOX);
  float*    csc    = (float*)(ws + WS_CSC);
  int*      key    = (int*)(ws + WS_KEY);
  int*      ccl    = (int*)(ws + WS_CCLS);

  static const int HWs[5] = {10000, 2500, 625, 169, 49};

  hipMemsetAsync(ws + WS_HIST, 0, 655680, stream);

  for (int i = 0; i < 5; i++)
    pool_k<<<NIMG*256, 256, 0, stream>>>(feat[i], pooled, HWs[i], i*256);
  linear_k<<<NIMG*30, 256, 0, stream>>>(pooled, lw, lb, out);

  for (int i = 0; i < 5; i++){
    int E = 720 * HWs[i];
    int E4 = E / 4;
    int bpi = (E4 + 32768 - 1) / 32768;
    hist_k<<<NIMG*bpi, 256, 0, stream>>>(cls[i], hist + (size_t)i*NIMG*NBIN, E4, bpi);
  }
  cutoff_k<<<NLVL*NIMG, 256, 0, stream>>>(hist, cut);
  for (int i = 0; i < 5; i++){
    int E = 720 * HWs[i];
    int bpi = (E + 65536 - 1) / 65536;
    compact_k<<<NIMG*bpi, 256, 0, stream>>>(cls[i], cut, sel, selcnt, bnd, bndcnt,
                                            E, HWs[i], bpi, i);
  }
  bsel_k<<<NLVL*NIMG, 256, 0, stream>>>(cut, sel, bnd, bndcnt);

  LvlArgs la;
  for (int i = 0; i < 5; i++){ la.delta[i] = del[i]; la.anc[i] = anc[i]; la.HW[i] = HWs[i]; }
  decode_k<<<(NLVL*NIMG*TK + 255)/256, 256, 0, stream>>>(sel, la, cbox, obox, csc, key, ccl);
  nms2_k<<<NIMG, 256, 0, stream>>>(cbox, obox, csc, key, ccl, out);
}